// Round 10
// baseline (4669.755 us; speedup 1.0000x reference)
//
#include <hip/hip_runtime.h>
#include <hip/hip_bf16.h>

// SimpleLSTM on MI355X — round 13: COALESCED exchange (transposed layout + LDS).
//   B=64, S=512, I=512, H=1024, gates = 4H = 4096
// R12 post-mortem: phase-alternation serialized two groups in one block; step
// time = full macro (3907us). Reverted. Invariant across R4-R12 (~4.6us/step):
// consumer reads h by batch-row -> lane stride 4KB -> every 8B tagged load is
// its own L1-bypassed line transaction (~1024/block/sweep, 12% payload). The
// floor is LLC small-transaction throughput (explains R4->R8 null: tags
// doubled bytes while batches halved -> transaction count unchanged).
// R13 = R8 with the exchange COALESCED:
//   * publish layout transposed to [col][batch]: block's 256 words = 1KB
//     contiguous region
//   * cooperative poll: 512 threads x 8 interleaved u64 agent-atomic loads;
//     each instruction covers 4KB contiguous -> full 64B lines, ~512
//     transactions/block/sweep (8x fewer, 100% payload)
//   * passed words staged to bank-padded LDS (idx = word + 8*(word>>6)):
//     frag gathers hit all 32 banks conflict-free; A-rows 8-15 read
//     duplicates of 0-7 (their D-rows are discarded -> harmless)
//   * everything else R8 verbatim: geometry, tags (bf16<<16|epoch), wh/wx0
//     regs + wxl LDS, gtile reduction, 2 barriers/step (bar A also guards
//     gtile reuse), publish-after-bar-B keeps the transitive reuse proof

#define BATCH 64
#define SEQ   512
#define ISZ   512
#define HSZ   1024
#define G4    4096

#define NGRP  8
#define GB    8      // batches per group
#define SLOTS 32     // CUs per group

typedef short bf16x8 __attribute__((ext_vector_type(8)));
typedef float f32x4  __attribute__((ext_vector_type(4)));

#define HEX_DW (NGRP * 2 * GB * HSZ)   // 131072 tagged dwords = 512 KB

static __device__ __forceinline__ short f2bf(float f) {
    __hip_bfloat16 h = __float2bfloat16(f);
    return *reinterpret_cast<short*>(&h);
}
static __device__ __forceinline__ float sigm(float x) {
    return 1.f / (1.f + __expf(-x));
}
static __device__ __forceinline__ float tanh_fast(float x) {
    x = fminf(15.f, fmaxf(-15.f, x));
    float e = __expf(2.f * x);
    return (e - 1.f) / (e + 1.f);
}

__global__ __launch_bounds__(512, 2) void lstm_persistent(
    const float* __restrict__ x,     // [B][S][I] fp32
    const float* __restrict__ W,     // [I+H][4H] fp32
    const float* __restrict__ bias,  // [4H] fp32
    float* __restrict__ out,         // [B][S][H], then [B][H] h, [B][H] c
    unsigned int* __restrict__ hx)   // [NGRP][2][1024][8] tagged words (col-major!)
{
    const int tid  = threadIdx.x;
    const int bid  = blockIdx.x;
    const int g    = bid & 7;           // group
    const int s    = bid >> 3;          // slot 0..31: owns h-cols [32s, 32s+32)
    const int w    = tid >> 6;          // wave 0..7 = h-K slice [128w, +128)
    const int lane = tid & 63;
    const int m16  = lane & 15;
    const int quad = lane >> 4;

    __shared__ short wxl[8][8][64][8];      // Wx kk=1 frags, 64 KB (self-wave read)
    __shared__ float gtile[8][8][8][16];    // 8 waves x 8 col-tiles x 8 rows, 32 KB
    __shared__ unsigned int hbuf[9216];     // staged h words, bank-padded, 36 KB

    // ---- preload weights as MFMA B-fragments ----
    // slot s: 8 col-tiles ct -> col = (ct>>1)*1024 + s*32 + (ct&1)*16
    // B-frag (16x16x32): lane holds B[k = quad*8 + j][n = lane&15]
    bf16x8 wh[8][4];
    bf16x8 wx0[8];
    #pragma unroll
    for (int ct = 0; ct < 8; ++ct) {
        const int col = (ct >> 1) * 1024 + s * 32 + (ct & 1) * 16 + m16;
        #pragma unroll
        for (int kk = 0; kk < 4; ++kk)
            #pragma unroll
            for (int j = 0; j < 8; ++j)
                wh[ct][kk][j] = f2bf(W[(size_t)(ISZ + w * 128 + kk * 32 + quad * 8 + j) * G4 + col]);
        bf16x8 t0, t1;
        #pragma unroll
        for (int j = 0; j < 8; ++j) {
            t0[j] = f2bf(W[(size_t)(w * 64 + quad * 8 + j) * G4 + col]);
            t1[j] = f2bf(W[(size_t)(w * 64 + 32 + quad * 8 + j) * G4 + col]);
        }
        wx0[ct] = t0;
        *(bf16x8*)&wxl[w][ct][lane][0] = t1;
    }

    // elementwise mapping (tid < 256): eb = batch-in-group, ec = h-col-in-32
    const int eb = tid >> 5;
    const int ec = tid & 31;
    float bia[4] = {0.f, 0.f, 0.f, 0.f};
    if (tid < 256) {
        #pragma unroll
        for (int gg2 = 0; gg2 < 4; ++gg2) bia[gg2] = bias[gg2 * 1024 + s * 32 + ec];
    }
    float c_state = 0.f;

    f32x4 acc[8];
    f32x4 xr0 = {0,0,0,0}, xr1 = {0,0,0,0}, xr2 = {0,0,0,0}, xr3 = {0,0,0,0};

    auto xload = [&](int tt) {
        if (m16 < 8) {
            const float* xp = x + ((size_t)(g * GB + m16) * SEQ + tt) * ISZ
                                + w * 64 + quad * 8;
            xr0 = *(const f32x4*)xp;
            xr1 = *(const f32x4*)(xp + 4);
            xr2 = *(const f32x4*)(xp + 32);
            xr3 = *(const f32x4*)(xp + 36);
        }
    };
    auto xmfma = [&]() {
        #pragma unroll
        for (int ct = 0; ct < 8; ++ct) acc[ct] = (f32x4){0.f, 0.f, 0.f, 0.f};
        bf16x8 a0, a1;
        a0[0]=f2bf(xr0[0]); a0[1]=f2bf(xr0[1]); a0[2]=f2bf(xr0[2]); a0[3]=f2bf(xr0[3]);
        a0[4]=f2bf(xr1[0]); a0[5]=f2bf(xr1[1]); a0[6]=f2bf(xr1[2]); a0[7]=f2bf(xr1[3]);
        a1[0]=f2bf(xr2[0]); a1[1]=f2bf(xr2[1]); a1[2]=f2bf(xr2[2]); a1[3]=f2bf(xr2[3]);
        a1[4]=f2bf(xr3[0]); a1[5]=f2bf(xr3[1]); a1[6]=f2bf(xr3[2]); a1[7]=f2bf(xr3[3]);
        #pragma unroll
        for (int ct = 0; ct < 8; ++ct)
            acc[ct] = __builtin_amdgcn_mfma_f32_16x16x32_bf16(a0, wx0[ct], acc[ct], 0, 0, 0);
        #pragma unroll
        for (int ct = 0; ct < 8; ++ct) {
            bf16x8 bx = *(const bf16x8*)&wxl[w][ct][lane][0];
            acc[ct] = __builtin_amdgcn_mfma_f32_16x16x32_bf16(a1, bx, acc[ct], 0, 0, 0);
        }
    };

    __syncthreads();   // wxl staged
    xload(0);
    xmfma();           // acc holds x-part of t=0

    for (int t = 0; t < SEQ; ++t) {
        // ---- cooperative coalesced poll (t=0 passes: zeros == tag 0, h=0) ----
        const unsigned int tg = (unsigned int)t & 0xFFFFu;
        const int rb = (t + 1) & 1;
        const unsigned long long* src = (const unsigned long long*)
            (hx + ((size_t)g * 2 + rb) * 8192);

        {
            unsigned long long pv[8];
            long long guard = 0;
            for (;;) {
                unsigned int bad = 0;
                #pragma unroll
                for (int i = 0; i < 8; ++i) {
                    pv[i] = __hip_atomic_load(src + (size_t)i * 512 + tid,
                        __ATOMIC_RELAXED, __HIP_MEMORY_SCOPE_AGENT);
                    bad |= ((unsigned int)pv[i] ^ tg)
                         | ((unsigned int)(pv[i] >> 32) ^ tg);
                }
                if (__all((int)((bad & 0xFFFFu) == 0u))) break;
                __builtin_amdgcn_s_sleep(1);
                if (++guard > (1LL << 22)) break;   // safety valve (never trips)
            }
            // stage to bank-padded LDS: word pair (2k, 2k+1) -> idx = 2k + 8*(2k>>6)
            #pragma unroll
            for (int i = 0; i < 8; ++i) {
                const int word = (i * 512 + tid) * 2;
                const int idx  = word + 8 * (word >> 6);
                *(unsigned long long*)&hbuf[idx] = pv[i];
            }
        }
        __syncthreads();   // bar A: hbuf complete (also guards gtile reuse)

        // ---- h-MFMA: A-frags gathered from LDS (conflict-free banks) ----
        {
            const int mb = m16 & 7;   // batch (rows 8-15 duplicate: D discarded)
            #pragma unroll
            for (int kk = 0; kk < 4; ++kk) {
                bf16x8 ha;
                #pragma unroll
                for (int j = 0; j < 8; ++j) {
                    const int word = w * 1024 + kk * 256 + quad * 64 + j * 8 + mb;
                    const int idx  = word + 8 * (w * 16 + kk * 4 + quad);
                    ha[j] = (short)(hbuf[idx] >> 16);
                }
                #pragma unroll
                for (int ct = 0; ct < 8; ++ct)
                    acc[ct] = __builtin_amdgcn_mfma_f32_16x16x32_bf16(ha, wh[ct][kk], acc[ct], 0, 0, 0);
            }
        }

        // ---- partials -> LDS (C/D: col = lane&15, row = quad*4 + r; rows 0-7 real) ----
        if (quad < 2) {
            #pragma unroll
            for (int ct = 0; ct < 8; ++ct)
                #pragma unroll
                for (int r = 0; r < 4; ++r)
                    gtile[w][ct][quad * 4 + r][m16] = acc[ct][r];
        }
        __syncthreads();   // bar B

        // ---- elementwise gates + publish (transposed, coalesced) + out ----
        if (tid < 256) {
            float gv[4];
            #pragma unroll
            for (int gg2 = 0; gg2 < 4; ++gg2) {
                const int ct = gg2 * 2 + (ec >> 4);
                const int cn = ec & 15;
                float ss = bia[gg2];
                #pragma unroll
                for (int ww = 0; ww < 8; ++ww) ss += gtile[ww][ct][eb][cn];
                gv[gg2] = ss;
            }
            float f  = sigm(gv[0]);
            float i  = sigm(gv[1]);
            float cc = tanh_fast(gv[2]);
            float o  = sigm(gv[3]);
            c_state  = f * c_state + i * cc;
            float h_val = o * tanh_fast(c_state);
            unsigned int pword = ((unsigned int)(unsigned short)f2bf(h_val) << 16)
                               | ((unsigned int)(t + 1) & 0xFFFFu);

            // pair batches eb, eb^1 (lane^32) -> 8B store at [col][batch]
            unsigned int ow = __shfl_xor(pword, 32, 64);
            if (!(eb & 1)) {
                unsigned long long pk = (unsigned long long)pword
                                      | ((unsigned long long)ow << 32);
                unsigned long long* dst = (unsigned long long*)
                    (hx + ((size_t)g * 2 + (t & 1)) * 8192) 
                    + ((size_t)(s * 32 + ec) * 4 + (eb >> 1));
                __hip_atomic_store(dst, pk,
                                   __ATOMIC_RELAXED, __HIP_MEMORY_SCOPE_AGENT);
            }
            // off-critical-path output stores
            out[((size_t)(g * GB + eb) * SEQ + t) * HSZ + s * 32 + ec] = h_val;
            if (t == SEQ - 1) {
                size_t fin = (size_t)BATCH * SEQ * HSZ;
                out[fin + (size_t)(g * GB + eb) * HSZ + s * 32 + ec] = h_val;
                out[fin + (size_t)BATCH * HSZ + (size_t)(g * GB + eb) * HSZ
                        + s * 32 + ec] = c_state;
            }
        }

        // ---- x part for t+1 (R8 tail kept verbatim) ----
        if (t + 1 < SEQ) { xload(t + 1); xmfma(); }
    }
}

extern "C" void kernel_launch(void* const* d_in, const int* in_sizes, int n_in,
                              void* d_out, int out_size, void* d_ws, size_t ws_size,
                              hipStream_t stream) {
    const float* x    = (const float*)d_in[0];
    const float* W    = (const float*)d_in[1];
    const float* bias = (const float*)d_in[2];
    float* out        = (float*)d_out;

    unsigned int* hx = (unsigned int*)d_ws;

    // zero tagged exchange: epoch 0 == valid h0 = 0
    hipMemsetAsync(d_ws, 0, HEX_DW * 4, stream);

    lstm_persistent<<<256, 512, 0, stream>>>(x, W, bias, out, hx);
}

// Round 11
// 1909.697 us; speedup vs baseline: 2.4453x; 2.4453x over previous
//
#include <hip/hip_runtime.h>
#include <hip/hip_bf16.h>

// SimpleLSTM on MI355X — round 14: flag-gated UNTAGGED payload (kill spin traffic).
//   B=64, S=512, I=512, H=1024, gates = 4H = 4096
// R13 post-mortem: coalesced whole-block poll coupled blocks to slowest
// producer + transposed partial-line stores doubled WRITE_SIZE -> 4670us.
// Reverted. Traffic audit across R4-R13: in R8 ~85% of exchange reads are
// FAILED-SWEEP RE-READS (4KB per wave per spin iter); 2048 spinning waves
// congest the fabric that publish-visibility itself depends on.
// R14 = R8 geometry/compute with the exchange protocol split:
//   * producers publish UNTAGGED bf16 (half the bytes; dense 64B lines),
//     barrier vmcnt(0) drains them, then ONE 4B epoch flag per slot
//     (R4-proven store-after-drain protocol)
//   * consumers spin on 4 flag words only (4 lanes x 4B, ~1 line/sweep)
//     then read payload ONCE: 4x global_load_dwordx4 sc0 sc1 per lane
//   * untagged 16B load == one MFMA A-fragment verbatim: zero extraction
//     VALU (R8 spent ~64 shifts/step stripping tags)
//   * reuse safety unchanged: flag >= t+1 transitively proves all step-t-1
//     payload reads completed before any h@{t+1} overwrite
// Unchanged: 8 groups x 32 slots x 8 batches, wh/wx0 regs + wxl LDS, gtile
// reduction, 2 barriers/step, xpart tail, launch_bounds(512,2).

#define BATCH 64
#define SEQ   512
#define ISZ   512
#define HSZ   1024
#define G4    4096

#define NGRP  8
#define GB    8      // batches per group
#define SLOTS 32     // CUs per group

typedef short bf16x8 __attribute__((ext_vector_type(8)));
typedef float f32x4  __attribute__((ext_vector_type(4)));
typedef unsigned int u32x4 __attribute__((ext_vector_type(4)));

#define HEX_SHORTS (NGRP * 2 * GB * HSZ)          // 131072 bf16 = 256 KB
#define HEX_BYTES  (HEX_SHORTS * 2)
#define FLAG_DW    (NGRP * SLOTS)                 // packed 4B flags, 128B/group
#define WS_BYTES   (HEX_BYTES + FLAG_DW * 4)

static __device__ __forceinline__ short f2bf(float f) {
    __hip_bfloat16 h = __float2bfloat16(f);
    return *reinterpret_cast<short*>(&h);
}
static __device__ __forceinline__ float sigm(float x) {
    return 1.f / (1.f + __expf(-x));
}
static __device__ __forceinline__ float tanh_fast(float x) {
    x = fminf(15.f, fmaxf(-15.f, x));
    float e = __expf(2.f * x);
    return (e - 1.f) / (e + 1.f);
}

__global__ __launch_bounds__(512, 2) void lstm_persistent(
    const float* __restrict__ x,     // [B][S][I] fp32
    const float* __restrict__ W,     // [I+H][4H] fp32
    const float* __restrict__ bias,  // [4H] fp32
    float* __restrict__ out,         // [B][S][H], then [B][H] h, [B][H] c
    unsigned short* __restrict__ hex,// [NGRP][2][GB][HSZ] bf16 (untagged)
    unsigned int* __restrict__ flags)// [NGRP][SLOTS] epoch flags, packed
{
    const int tid  = threadIdx.x;
    const int bid  = blockIdx.x;
    const int g    = bid & 7;           // group
    const int s    = bid >> 3;          // slot 0..31: owns h-cols [32s, 32s+32)
    const int w    = tid >> 6;          // wave 0..7 = h-K slice [128w, +128)
    const int lane = tid & 63;
    const int m16  = lane & 15;
    const int quad = lane >> 4;

    __shared__ short wxl[8][8][64][8];      // Wx kk=1 frags, 64 KB (self-wave read)
    __shared__ float gtile[8][8][8][16];    // 8 waves x 8 col-tiles x 8 rows, 32 KB

    // ---- preload weights as MFMA B-fragments ----
    // slot s: 8 col-tiles ct -> col = (ct>>1)*1024 + s*32 + (ct&1)*16
    // B-frag (16x16x32): lane holds B[k = quad*8 + j][n = lane&15]
    bf16x8 wh[8][4];
    bf16x8 wx0[8];
    #pragma unroll
    for (int ct = 0; ct < 8; ++ct) {
        const int col = (ct >> 1) * 1024 + s * 32 + (ct & 1) * 16 + m16;
        #pragma unroll
        for (int kk = 0; kk < 4; ++kk)
            #pragma unroll
            for (int j = 0; j < 8; ++j)
                wh[ct][kk][j] = f2bf(W[(size_t)(ISZ + w * 128 + kk * 32 + quad * 8 + j) * G4 + col]);
        bf16x8 t0, t1;
        #pragma unroll
        for (int j = 0; j < 8; ++j) {
            t0[j] = f2bf(W[(size_t)(w * 64 + quad * 8 + j) * G4 + col]);
            t1[j] = f2bf(W[(size_t)(w * 64 + 32 + quad * 8 + j) * G4 + col]);
        }
        wx0[ct] = t0;
        *(bf16x8*)&wxl[w][ct][lane][0] = t1;
    }

    // elementwise mapping (tid < 256): eb = batch-in-group, ec = h-col-in-32
    const int eb = tid >> 5;
    const int ec = tid & 31;
    float bia[4] = {0.f, 0.f, 0.f, 0.f};
    if (tid < 256) {
        #pragma unroll
        for (int gg2 = 0; gg2 < 4; ++gg2) bia[gg2] = bias[gg2 * 1024 + s * 32 + ec];
    }
    float c_state = 0.f;

    unsigned short* hexg  = hex + (size_t)g * (2 * GB * HSZ);
    unsigned int*   gflag = flags + (size_t)g * SLOTS;

    f32x4 acc[8];
    f32x4 xr0 = {0,0,0,0}, xr1 = {0,0,0,0}, xr2 = {0,0,0,0}, xr3 = {0,0,0,0};

    auto xload = [&](int tt) {
        if (m16 < 8) {
            const float* xp = x + ((size_t)(g * GB + m16) * SEQ + tt) * ISZ
                                + w * 64 + quad * 8;
            xr0 = *(const f32x4*)xp;
            xr1 = *(const f32x4*)(xp + 4);
            xr2 = *(const f32x4*)(xp + 32);
            xr3 = *(const f32x4*)(xp + 36);
        }
    };
    auto xmfma = [&]() {
        #pragma unroll
        for (int ct = 0; ct < 8; ++ct) acc[ct] = (f32x4){0.f, 0.f, 0.f, 0.f};
        bf16x8 a0, a1;
        a0[0]=f2bf(xr0[0]); a0[1]=f2bf(xr0[1]); a0[2]=f2bf(xr0[2]); a0[3]=f2bf(xr0[3]);
        a0[4]=f2bf(xr1[0]); a0[5]=f2bf(xr1[1]); a0[6]=f2bf(xr1[2]); a0[7]=f2bf(xr1[3]);
        a1[0]=f2bf(xr2[0]); a1[1]=f2bf(xr2[1]); a1[2]=f2bf(xr2[2]); a1[3]=f2bf(xr2[3]);
        a1[4]=f2bf(xr3[0]); a1[5]=f2bf(xr3[1]); a1[6]=f2bf(xr3[2]); a1[7]=f2bf(xr3[3]);
        #pragma unroll
        for (int ct = 0; ct < 8; ++ct)
            acc[ct] = __builtin_amdgcn_mfma_f32_16x16x32_bf16(a0, wx0[ct], acc[ct], 0, 0, 0);
        #pragma unroll
        for (int ct = 0; ct < 8; ++ct) {
            bf16x8 bx = *(const bf16x8*)&wxl[w][ct][lane][0];
            acc[ct] = __builtin_amdgcn_mfma_f32_16x16x32_bf16(a1, bx, acc[ct], 0, 0, 0);
        }
    };

    __syncthreads();   // wxl staged
    xload(0);
    xmfma();           // acc holds x-part of t=0

    for (int t = 0; t < SEQ; ++t) {
        // ---- 1. flag spin: wave w's 4 producers (slots 4w..4w+3) ----
        // tiny footprint: 4 lanes x 4B, ~1 line/sweep. t=0 passes (0 >= 0).
        {
            unsigned int v = ~0u;
            long long guard = 0;
            for (;;) {
                if (lane < 4)
                    v = __hip_atomic_load(gflag + 4 * w + lane,
                        __ATOMIC_RELAXED, __HIP_MEMORY_SCOPE_AGENT);
                if (__all((int)(v >= (unsigned int)t))) break;
                __builtin_amdgcn_s_sleep(1);
                if (++guard > (1LL << 22)) break;   // safety valve (never trips)
            }
        }

        // ---- 2. payload: ONE clean read; 16B load == one A-fragment ----
        const int rb = (t + 1) & 1;
        u32x4 q0 = {0,0,0,0}, q1 = {0,0,0,0}, q2 = {0,0,0,0}, q3 = {0,0,0,0};
        if (m16 < 8) {
            const unsigned short* hb = hexg + ((size_t)rb * GB + m16) * HSZ
                                            + w * 128 + quad * 8;
            asm volatile(
                "global_load_dwordx4 %0, %4, off sc0 sc1\n\t"
                "global_load_dwordx4 %1, %4, off offset:64 sc0 sc1\n\t"
                "global_load_dwordx4 %2, %4, off offset:128 sc0 sc1\n\t"
                "global_load_dwordx4 %3, %4, off offset:192 sc0 sc1\n\t"
                "s_waitcnt vmcnt(0)"
                : "=&v"(q0), "=&v"(q1), "=&v"(q2), "=&v"(q3)
                : "v"(hb)
                : "memory");
        }
        {
            union { u32x4 u; bf16x8 h; } c0, c1, c2, c3;
            c0.u = q0; c1.u = q1; c2.u = q2; c3.u = q3;
            #pragma unroll
            for (int ct = 0; ct < 8; ++ct)
                acc[ct] = __builtin_amdgcn_mfma_f32_16x16x32_bf16(c0.h, wh[ct][0], acc[ct], 0, 0, 0);
            #pragma unroll
            for (int ct = 0; ct < 8; ++ct)
                acc[ct] = __builtin_amdgcn_mfma_f32_16x16x32_bf16(c1.h, wh[ct][1], acc[ct], 0, 0, 0);
            #pragma unroll
            for (int ct = 0; ct < 8; ++ct)
                acc[ct] = __builtin_amdgcn_mfma_f32_16x16x32_bf16(c2.h, wh[ct][2], acc[ct], 0, 0, 0);
            #pragma unroll
            for (int ct = 0; ct < 8; ++ct)
                acc[ct] = __builtin_amdgcn_mfma_f32_16x16x32_bf16(c3.h, wh[ct][3], acc[ct], 0, 0, 0);
        }

        // ---- 3. partials -> LDS (C/D: col = lane&15, row = quad*4 + r) ----
        if (quad < 2) {
            #pragma unroll
            for (int ct = 0; ct < 8; ++ct)
                #pragma unroll
                for (int r = 0; r < 4; ++r)
                    gtile[w][ct][quad * 4 + r][m16] = acc[ct][r];
        }
        __syncthreads();   // bar A

        // ---- 4. elementwise gates + publish (before bar B) ----
        float h_val = 0.f;
        if (tid < 256) {
            float gv[4];
            #pragma unroll
            for (int gg2 = 0; gg2 < 4; ++gg2) {
                const int ct = gg2 * 2 + (ec >> 4);
                const int cn = ec & 15;
                float ss = bia[gg2];
                #pragma unroll
                for (int ww = 0; ww < 8; ++ww) ss += gtile[ww][ct][eb][cn];
                gv[gg2] = ss;
            }
            float f  = sigm(gv[0]);
            float i  = sigm(gv[1]);
            float cc = tanh_fast(gv[2]);
            float o  = sigm(gv[3]);
            c_state  = f * c_state + i * cc;
            h_val    = o * tanh_fast(c_state);

            // pack 4 cols -> one 8B agent store from lanes ec%4==0
            unsigned int hu = (unsigned int)(unsigned short)f2bf(h_val);
            unsigned int hn = __shfl_xor(hu, 1, 64);
            unsigned int p2 = hu | (hn << 16);
            unsigned long long p2o = (unsigned long long)__shfl_xor(p2, 2, 64);
            if ((ec & 3) == 0) {
                unsigned long long pk = (unsigned long long)p2 | (p2o << 32);
                __hip_atomic_store(
                    (unsigned long long*)(hexg + ((size_t)(t & 1) * GB + eb) * HSZ
                                              + s * 32 + ec),
                    pk, __ATOMIC_RELAXED, __HIP_MEMORY_SCOPE_AGENT);
            }
        }
        __syncthreads();   // bar B: drains publish stores (vmcnt(0) before barrier)

        // ---- 5. flag: publish visible => announce epoch t+1 ----
        if (tid == 0)
            __hip_atomic_store(gflag + s, (unsigned int)(t + 1),
                               __ATOMIC_RELAXED, __HIP_MEMORY_SCOPE_AGENT);

        // ---- 6. off-critical-path output stores ----
        if (tid < 256) {
            out[((size_t)(g * GB + eb) * SEQ + t) * HSZ + s * 32 + ec] = h_val;
            if (t == SEQ - 1) {
                size_t fin = (size_t)BATCH * SEQ * HSZ;
                out[fin + (size_t)(g * GB + eb) * HSZ + s * 32 + ec] = h_val;
                out[fin + (size_t)BATCH * HSZ + (size_t)(g * GB + eb) * HSZ
                        + s * 32 + ec] = c_state;
            }
        }

        // ---- 7. x part for t+1 ----
        if (t + 1 < SEQ) { xload(t + 1); xmfma(); }
    }
}

extern "C" void kernel_launch(void* const* d_in, const int* in_sizes, int n_in,
                              void* d_out, int out_size, void* d_ws, size_t ws_size,
                              hipStream_t stream) {
    const float* x    = (const float*)d_in[0];
    const float* W    = (const float*)d_in[1];
    const float* bias = (const float*)d_in[2];
    float* out        = (float*)d_out;

    unsigned short* hex   = (unsigned short*)d_ws;
    unsigned int*   flags = (unsigned int*)((char*)d_ws + HEX_BYTES);

    // zero exchange (h0 = 0) + flags (epoch 0)
    hipMemsetAsync(d_ws, 0, WS_BYTES, stream);

    lstm_persistent<<<256, 512, 0, stream>>>(x, W, bias, out, hex, flags);
}